// Round 23
// baseline (350.113 us; speedup 1.0000x reference)
//
#include <hip/hip_runtime.h>
#include <math.h>

#define H 300
#define NLEAF 4096

typedef unsigned int  uint;
typedef unsigned short ushort;
typedef __attribute__((ext_vector_type(8))) short  short8;
typedef __attribute__((ext_vector_type(4))) float  f32x4;

__device__ __forceinline__ float sigmoidf_(float x) { return 1.0f / (1.0f + expf(-x)); }

__device__ __forceinline__ ushort f2bf(float f)
{
    uint u = __float_as_uint(f);
    u += 0x7FFF + ((u >> 16) & 1);
    return (ushort)(u >> 16);
}
__device__ __forceinline__ uint2 pack4(float4 v)
{
    uint2 w;
    w.x = (uint)f2bf(v.x) | ((uint)f2bf(v.y) << 16);
    w.y = (uint)f2bf(v.z) | ((uint)f2bf(v.w) << 16);
    return w;
}

// ---- per-wave MFMA GEMM over FRAGMENT-TILED B ----
// B tiled as [colTile][kstep][512 ushorts]: fragment (tile,s) contiguous 1024B;
// lane l reads short8 at frag + l*8 — fully coalesced (16B/lane).
// A in LDS (row stride AS): row=lane%16, k=(s0+s)*32+(lane>>4)*8+i.
// C/D col=lane&15, row=(lane>>4)*4+reg (m89-verified).
template<int NT, int KSTEPS, int KT, int AS>
__device__ __forceinline__ void mfma_gemm(const ushort* A_lds, const ushort* __restrict__ Bt,
                                          int tile0, int s0, int lane, f32x4* acc)
{
    const ushort* Ap = A_lds + (lane & 15) * AS + ((lane >> 4) * 8) + s0 * 32;
    const ushort* Bp[NT];
    #pragma unroll
    for (int t = 0; t < NT; ++t)
        Bp[t] = Bt + ((long)(tile0 + t) * KT + s0) * 512 + lane * 8;

    short8 aA, aB, bA[NT], bB[NT];
    aA = *(const short8*)Ap;
    #pragma unroll
    for (int t = 0; t < NT; ++t) bA[t] = *(const short8*)Bp[t];

    int s = 0;
    #pragma unroll 1
    for (; s + 2 < KSTEPS; s += 2) {
        aB = *(const short8*)(Ap + (s + 1) * 32);
        #pragma unroll
        for (int t = 0; t < NT; ++t) bB[t] = *(const short8*)(Bp[t] + (s + 1) * 512);
        #pragma unroll
        for (int t = 0; t < NT; ++t)
            acc[t] = __builtin_amdgcn_mfma_f32_16x16x32_bf16(aA, bA[t], acc[t], 0, 0, 0);
        aA = *(const short8*)(Ap + (s + 2) * 32);
        #pragma unroll
        for (int t = 0; t < NT; ++t) bA[t] = *(const short8*)(Bp[t] + (s + 2) * 512);
        #pragma unroll
        for (int t = 0; t < NT; ++t)
            acc[t] = __builtin_amdgcn_mfma_f32_16x16x32_bf16(aB, bB[t], acc[t], 0, 0, 0);
    }
    if (KSTEPS - s == 2) {
        aB = *(const short8*)(Ap + (s + 1) * 32);
        #pragma unroll
        for (int t = 0; t < NT; ++t) bB[t] = *(const short8*)(Bp[t] + (s + 1) * 512);
        #pragma unroll
        for (int t = 0; t < NT; ++t)
            acc[t] = __builtin_amdgcn_mfma_f32_16x16x32_bf16(aA, bA[t], acc[t], 0, 0, 0);
        #pragma unroll
        for (int t = 0; t < NT; ++t)
            acc[t] = __builtin_amdgcn_mfma_f32_16x16x32_bf16(aB, bB[t], acc[t], 0, 0, 0);
    } else {
        #pragma unroll
        for (int t = 0; t < NT; ++t)
            acc[t] = __builtin_amdgcn_mfma_f32_16x16x32_bf16(aA, bA[t], acc[t], 0, 0, 0);
    }
}

// ---- merged prep: tiled-bf16 weights (blocks 0-639) + tags (640-699) + flags
__global__ __launch_bounds__(256) void prep_k(
    const float* __restrict__ Wr, const float* __restrict__ Wz,
    const float* __restrict__ Wu, const float* __restrict__ tag_table,
    const float* __restrict__ br, const float* __restrict__ bz,
    ushort* __restrict__ WArzT, ushort* __restrict__ WuTpT, ushort* __restrict__ WLzuT,
    float* __restrict__ tag_r, float* __restrict__ tag_z, uint* __restrict__ flags)
{
    __shared__ float te[50];
    int b = blockIdx.x;
    int tid = threadIdx.x;
    if (b < 640) {
        int c = b;
        int tile = c >> 4, cl = c & 15;
        int gate = (c >= 320);
        int cc = gate ? c - 320 : c;
        const float* WA = gate ? Wz : Wr;
        for (int o = tid; o < 76; o += 256) {
            int k0 = o * 8;
            ushort tmp[8];
            #pragma unroll
            for (int i = 0; i < 8; ++i) {
                int k = k0 + i;
                float v = 0.f;
                if (cc < 300) {
                    if (k < 300) v = WA[(350 + k) * H + cc];
                    else if (k >= 304 && k < 604) v = WA[(k + 346) * H + cc];
                }
                tmp[i] = f2bf(v);
            }
            int s = k0 >> 5, kk0 = k0 & 31;
            long pos = ((long)(tile * 19 + s)) * 512 + ((kk0 >> 3) * 16 + cl) * 8;
            uint4 w;
            w.x = (uint)tmp[0] | ((uint)tmp[1] << 16);
            w.y = (uint)tmp[2] | ((uint)tmp[3] << 16);
            w.z = (uint)tmp[4] | ((uint)tmp[5] << 16);
            w.w = (uint)tmp[6] | ((uint)tmp[7] << 16);
            *(uint4*)&WArzT[pos] = w;
        }
        const float* WL = gate ? Wu : Wz;
        for (int o = tid; o < 40; o += 256) {
            int k0 = o * 8;
            ushort tmp[8];
            #pragma unroll
            for (int i = 0; i < 8; ++i) {
                int k = k0 + i;
                float v = (cc < 300 && k < 300) ? WL[k * H + cc] : 0.f;
                tmp[i] = f2bf(v);
            }
            int s = k0 >> 5, kk0 = k0 & 31;
            long pos = ((long)(tile * 10 + s)) * 512 + ((kk0 >> 3) * 16 + cl) * 8;
            uint4 w;
            w.x = (uint)tmp[0] | ((uint)tmp[1] << 16);
            w.y = (uint)tmp[2] | ((uint)tmp[3] << 16);
            w.z = (uint)tmp[4] | ((uint)tmp[5] << 16);
            w.w = (uint)tmp[6] | ((uint)tmp[7] << 16);
            *(uint4*)&WLzuT[pos] = w;
        }
        if (c < 320) {
            for (int o = tid; o < 76; o += 256) {
                int k0 = o * 8;
                ushort tmp[8];
                #pragma unroll
                for (int i = 0; i < 8; ++i) {
                    int k = k0 + i;
                    float v = 0.f;
                    if (c < 300) {
                        if (k < 300) v = Wu[(300 + k) * H + c];
                        else if (k >= 304 && k < 604) v = Wu[(k + 296) * H + c];
                    }
                    tmp[i] = f2bf(v);
                }
                int s = k0 >> 5, kk0 = k0 & 31;
                long pos = ((long)(tile * 19 + s)) * 512 + ((kk0 >> 3) * 16 + cl) * 8;
                uint4 w;
                w.x = (uint)tmp[0] | ((uint)tmp[1] << 16);
                w.y = (uint)tmp[2] | ((uint)tmp[3] << 16);
                w.z = (uint)tmp[4] | ((uint)tmp[5] << 16);
                w.w = (uint)tmp[6] | ((uint)tmp[7] << 16);
                *(uint4*)&WuTpT[pos] = w;
            }
        }
    } else {
        int t = b - 640;                 // 0..59
        if (b == 640) {
            for (int i = tid; i < 512; i += 256) flags[i] = 0u;
        }
        if (tid < 50) te[tid] = tag_table[t * 50 + tid];
        __syncthreads();
        for (int k = tid; k < H; k += 256) {
            float ar = br[k], az = bz[k];
            #pragma unroll 10
            for (int j = 0; j < 50; ++j) {
                float tv = te[j];
                ar = fmaf(tv, Wr[(H + j) * H + k], ar);
                az = fmaf(tv, Wz[(H + j) * H + k], az);
            }
            tag_r[t * H + k] = ar;
            tag_z[t * H + k] = az;
        }
    }
}

// ---- Leaf (MFMA, 512 thr / 8 waves): waves 0-3 z-cols, waves 4-7 u-cols.
__global__ __launch_bounds__(512, 1) void leaf_mfma_k(
    const int* __restrict__ word_ids, const int* __restrict__ tag_ids,
    const float* __restrict__ word_table, const ushort* __restrict__ WLzuT,
    const float* __restrict__ bu, const float* __restrict__ tag_z,
    float* __restrict__ out)
{
    __shared__ ushort Abf[16 * 328];
    __shared__ float zbuf[16][304];
    int tid = threadIdx.x;
    int node0 = blockIdx.x * 16;

    for (int idx = tid; idx < 16 * 82; idx += 512) {
        int j = idx / 82, q = idx - j * 82;
        char* rowb = (char*)(Abf + j * 328);
        if (q < 75) {
            float4 v = ((const float4*)(word_table + (long)word_ids[node0 + j] * H))[q];
            *(uint2*)(rowb + q * 8) = pack4(v);
        } else {
            *(uint2*)(rowb + q * 8) = make_uint2(0u, 0u);
        }
    }
    __syncthreads();

    int wv = tid >> 6, lane = tid & 63;
    int jrow = (lane >> 4) * 4;

    f32x4 acc[5];
    #pragma unroll
    for (int t = 0; t < 5; ++t) acc[t] = (f32x4)(0.f);

    if (wv < 4) {
        mfma_gemm<5, 10, 10, 328>(Abf, WLzuT, wv * 5, 0, lane, acc);
        int tg[4];
        #pragma unroll
        for (int q = 0; q < 4; ++q) tg[q] = tag_ids[node0 + jrow + q];
        #pragma unroll
        for (int t = 0; t < 5; ++t) {
            int c = wv * 80 + t * 16 + (lane & 15);
            #pragma unroll
            for (int q = 0; q < 4; ++q)
                if (c < 300) zbuf[jrow + q][c] = sigmoidf_(acc[t][q] + tag_z[tg[q] * H + c]);
        }
    } else {
        mfma_gemm<5, 10, 10, 328>(Abf, WLzuT, 20 + (wv - 4) * 5, 0, lane, acc);
    }
    __syncthreads();
    if (wv >= 4) {
        #pragma unroll
        for (int t = 0; t < 5; ++t) {
            int c = (wv - 4) * 80 + t * 16 + (lane & 15);
            #pragma unroll
            for (int q = 0; q < 4; ++q) {
                if (c < 300) {
                    int jn = jrow + q;
                    float u = tanhf(acc[t][q] + bu[c]);
                    out[(long)(node0 + jn) * H + c] = (1.f - zbuf[jn][c]) * u;
                }
            }
        }
    }
}

// ---- Fused internal level (512 thr / 8 waves, 16 nodes), for m >= 256 ----
__device__ __forceinline__ void fused_body(
    const int* __restrict__ tag_ids, const ushort* __restrict__ WArzT,
    const ushort* __restrict__ WuTpT, const float* __restrict__ bu,
    const float* __restrict__ tag_r, const float* __restrict__ tag_z,
    float* __restrict__ out, int off, int prevOff, int m,
    int node0, int tid, ushort* Abf, float (*zbuf)[304], float (*pbuf)[64][21])
{
    for (int idx = tid; idx < 16 * 154; idx += 512) {
        int j = idx / 154, q = idx - j * 154;
        char* rowb = (char*)(Abf + j * 616);
        bool valid = (node0 + j) < m;
        if (q < 75) {
            uint2 w = make_uint2(0u, 0u);
            if (valid) {
                float4 v = ((const float4*)(out + (long)(prevOff + 2 * (node0 + j)) * H))[q];
                w = pack4(v);
            }
            *(uint2*)(rowb + q * 8) = w;
        } else if (q < 150) {
            int qq = q - 75;
            uint2 w = make_uint2(0u, 0u);
            if (valid) {
                float4 v = ((const float4*)(out + (long)(prevOff + 2 * (node0 + j) + 1) * H))[qq];
                w = pack4(v);
            }
            *(uint2*)(rowb + 608 + qq * 8) = w;
        } else {
            int pb = (q == 150) ? 600 : (1208 + (q - 151) * 8);
            *(uint2*)(rowb + pb) = make_uint2(0u, 0u);
        }
    }
    __syncthreads();

    int wv = tid >> 6, lane = tid & 63;
    int jrow = (lane >> 4) * 4;
    int tg[4];
    #pragma unroll
    for (int q = 0; q < 4; ++q) {
        int gn = node0 + jrow + q;
        tg[q] = tag_ids[off + (gn < m ? gn : 0)];
    }

    f32x4 accG[5];
    #pragma unroll
    for (int t = 0; t < 5; ++t) accG[t] = (f32x4)(0.f);
    mfma_gemm<5, 19, 19, 616>(Abf, WArzT, wv * 5, 0, lane, accG);
    __syncthreads();

    float Sr[5][4];
    if (wv < 4) {
        #pragma unroll
        for (int t = 0; t < 5; ++t) {
            int c = wv * 80 + t * 16 + (lane & 15);
            #pragma unroll
            for (int q = 0; q < 4; ++q) {
                int jn = jrow + q, gn = node0 + jn;
                if (c < 300 && gn < m) {
                    float lh = out[(long)(prevOff + 2 * gn) * H + c];
                    float rh = out[(long)(prevOff + 2 * gn + 1) * H + c];
                    float r  = sigmoidf_(accG[t][q] + tag_r[tg[q] * H + c]);
                    Sr[t][q] = lh + rh;
                    Abf[jn * 616 + c]       = f2bf(r * lh);
                    Abf[jn * 616 + 304 + c] = f2bf(r * rh);
                }
            }
        }
    } else {
        #pragma unroll
        for (int t = 0; t < 5; ++t) {
            int cz = (wv - 4) * 80 + t * 16 + (lane & 15);
            #pragma unroll
            for (int q = 0; q < 4; ++q) {
                int jn = jrow + q, gn = node0 + jn;
                if (cz < 300 && gn < m)
                    zbuf[jn][cz] = sigmoidf_(accG[t][q] + tag_z[tg[q] * H + cz]);
            }
        }
    }
    __syncthreads();

    f32x4 accU[5];
    #pragma unroll
    for (int t = 0; t < 5; ++t) accU[t] = (f32x4)(0.f);
    if (wv < 4) {
        mfma_gemm<5, 10, 19, 616>(Abf, WuTpT, wv * 5, 0, lane, accU);
    } else {
        mfma_gemm<5, 9, 19, 616>(Abf, WuTpT, (wv - 4) * 5, 10, lane, accU);
        #pragma unroll
        for (int t = 0; t < 5; ++t)
            #pragma unroll
            for (int q = 0; q < 4; ++q)
                pbuf[wv - 4][lane][t * 4 + q] = accU[t][q];
    }
    __syncthreads();
    if (wv < 4) {
        #pragma unroll
        for (int t = 0; t < 5; ++t) {
            int c = wv * 80 + t * 16 + (lane & 15);
            #pragma unroll
            for (int q = 0; q < 4; ++q) {
                int jn = jrow + q, gn = node0 + jn;
                if (c < 300 && gn < m) {
                    float a = accU[t][q] + pbuf[wv][lane][t * 4 + q];
                    float u = tanhf(a + bu[c]);
                    float z = zbuf[jn][c];
                    out[(long)(off + gn) * H + c] = z * Sr[t][q] + (1.f - z) * u;
                }
            }
        }
    }
}

__global__ __launch_bounds__(512, 1) void level_fused_k(
    const int* __restrict__ tag_ids, const ushort* __restrict__ WArzT,
    const ushort* __restrict__ WuTpT, const float* __restrict__ bu,
    const float* __restrict__ tag_r, const float* __restrict__ tag_z,
    float* __restrict__ out, int off, int prevOff, int m)
{
    __shared__ ushort Abf[16 * 616];
    __shared__ float zbuf[16][304];
    __shared__ float pbuf[4][64][21];
    fused_body(tag_ids, WArzT, WuTpT, bu, tag_r, tag_z, out, off, prevOff, m,
               blockIdx.x * 16, threadIdx.x, Abf, zbuf, pbuf);
}

// ---- Small-level split bodies (256 thr / 4 waves) ----
__device__ __forceinline__ void gates_body(
    const int* __restrict__ tag_ids, const ushort* __restrict__ WArzT,
    const float* __restrict__ tag_r, const float* __restrict__ tag_z,
    const float* __restrict__ out,
    float* __restrict__ zws, float* __restrict__ Sws, ushort* __restrict__ rxws,
    int off, int prevOff, int m, int mt, int cb, int tid,
    ushort* Abf, float (*pbuf)[64][20])
{
    int node0 = mt * 16;
    for (int idx = tid; idx < 16 * 154; idx += 256) {
        int j = idx / 154, q = idx - j * 154;
        char* rowb = (char*)(Abf + j * 616);
        bool valid = (node0 + j) < m;
        if (q < 75) {
            uint2 w = make_uint2(0u, 0u);
            if (valid) {
                float4 v = ((const float4*)(out + (long)(prevOff + 2 * (node0 + j)) * H))[q];
                w = pack4(v);
            }
            *(uint2*)(rowb + q * 8) = w;
        } else if (q < 150) {
            int qq = q - 75;
            uint2 w = make_uint2(0u, 0u);
            if (valid) {
                float4 v = ((const float4*)(out + (long)(prevOff + 2 * (node0 + j) + 1) * H))[qq];
                w = pack4(v);
            }
            *(uint2*)(rowb + 608 + qq * 8) = w;
        } else {
            int pb = (q == 150) ? 600 : (1208 + (q - 151) * 8);
            *(uint2*)(rowb + pb) = make_uint2(0u, 0u);
        }
    }
    __syncthreads();

    int wv = tid >> 6, lane = tid & 63;
    int tile0 = cb * 5;
    f32x4 acc[5];
    #pragma unroll
    for (int t = 0; t < 5; ++t) acc[t] = (f32x4)(0.f);
    if (wv == 0)      mfma_gemm<5, 5, 19, 616>(Abf, WArzT, tile0, 0,  lane, acc);
    else if (wv == 1) mfma_gemm<5, 5, 19, 616>(Abf, WArzT, tile0, 5,  lane, acc);
    else if (wv == 2) mfma_gemm<5, 5, 19, 616>(Abf, WArzT, tile0, 10, lane, acc);
    else              mfma_gemm<5, 4, 19, 616>(Abf, WArzT, tile0, 15, lane, acc);
    if (wv > 0) {
        #pragma unroll
        for (int t = 0; t < 5; ++t)
            #pragma unroll
            for (int q = 0; q < 4; ++q)
                pbuf[wv - 1][lane][t * 4 + q] = acc[t][q];
    }
    __syncthreads();
    if (wv == 0) {
        int jrow = (lane >> 4) * 4;
        #pragma unroll
        for (int t = 0; t < 5; ++t) {
            int c = cb * 80 + t * 16 + (lane & 15);
            #pragma unroll
            for (int q = 0; q < 4; ++q) {
                int jn = jrow + q, gn = node0 + jn;
                float a = acc[t][q] + pbuf[0][lane][t * 4 + q]
                        + pbuf[1][lane][t * 4 + q] + pbuf[2][lane][t * 4 + q];
                if (c < 320) {                      // r gate
                    if (c < 300 && gn < m) {
                        int tg = tag_ids[off + gn];
                        float r  = sigmoidf_(a + tag_r[tg * H + c]);
                        float lh = out[(long)(prevOff + 2 * gn) * H + c];
                        float rh = out[(long)(prevOff + 2 * gn + 1) * H + c];
                        Sws[gn * 304 + c] = lh + rh;
                        rxws[(long)gn * 608 + c]       = f2bf(r * lh);
                        rxws[(long)gn * 608 + 304 + c] = f2bf(r * rh);
                    } else if (c >= 300 && c < 304 && gn < m) {
                        rxws[(long)gn * 608 + c]       = 0;
                        rxws[(long)gn * 608 + 304 + c] = 0;
                    }
                } else {                            // z gate
                    int cz = c - 320;
                    if (cz < 300 && gn < m) {
                        int tg = tag_ids[off + gn];
                        zws[gn * 304 + cz] = sigmoidf_(a + tag_z[tg * H + cz]);
                    }
                }
            }
        }
    }
}

__device__ __forceinline__ void u_body(
    const ushort* __restrict__ WuTpT, const float* __restrict__ bu,
    const float* __restrict__ zws, const float* __restrict__ Sws,
    const ushort* __restrict__ rxws,
    float* __restrict__ out, int off, int m, float* __restrict__ dup,
    int mt, int ub, int tid, ushort* Abf, float (*pbuf)[64][20])
{
    int node0 = mt * 16;
    for (int idx = tid; idx < 16 * 77; idx += 256) {
        int j = idx / 77, q = idx - j * 77;
        uint4* dst = (uint4*)(Abf + j * 616) + q;
        if (q < 76 && (node0 + j) < m)
            *dst = ((const uint4*)(rxws + (long)(node0 + j) * 608))[q];
        else
            *dst = make_uint4(0u, 0u, 0u, 0u);
    }
    __syncthreads();

    int wv = tid >> 6, lane = tid & 63;
    int tile0 = ub * 5;
    f32x4 acc[5];
    #pragma unroll
    for (int t = 0; t < 5; ++t) acc[t] = (f32x4)(0.f);
    if (wv == 0)      mfma_gemm<5, 5, 19, 616>(Abf, WuTpT, tile0, 0,  lane, acc);
    else if (wv == 1) mfma_gemm<5, 5, 19, 616>(Abf, WuTpT, tile0, 5,  lane, acc);
    else if (wv == 2) mfma_gemm<5, 5, 19, 616>(Abf, WuTpT, tile0, 10, lane, acc);
    else              mfma_gemm<5, 4, 19, 616>(Abf, WuTpT, tile0, 15, lane, acc);
    if (wv > 0) {
        #pragma unroll
        for (int t = 0; t < 5; ++t)
            #pragma unroll
            for (int q = 0; q < 4; ++q)
                pbuf[wv - 1][lane][t * 4 + q] = acc[t][q];
    }
    __syncthreads();
    if (wv == 0) {
        int jrow = (lane >> 4) * 4;
        #pragma unroll
        for (int t = 0; t < 5; ++t) {
            int c = ub * 80 + t * 16 + (lane & 15);
            #pragma unroll
            for (int q = 0; q < 4; ++q) {
                int jn = jrow + q, gn = node0 + jn;
                if (c < 300 && gn < m) {
                    float a = acc[t][q] + pbuf[0][lane][t * 4 + q]
                            + pbuf[1][lane][t * 4 + q] + pbuf[2][lane][t * 4 + q];
                    float u = tanhf(a + bu[c]);
                    float z = zws[gn * 304 + c];
                    float h = z * Sws[gn * 304 + c] + (1.f - z) * u;
                    out[(long)(off + gn) * H + c] = h;
                    if (dup && gn == 0) dup[c] = h;
                }
            }
        }
    }
}

// ---- Chained small levels (m=128..1) in ONE launch: 228 blocks, 16 phases.
// v2 sync: flags padded 1/cacheline; consumers poll with coherent READ
// (__hip_atomic_load, no RMW); producers threadfence+atomicAdd (R17-validated).
__global__ __launch_bounds__(256, 1) void chain_k(
    const int* __restrict__ tag_ids, const ushort* __restrict__ WArzT,
    const ushort* __restrict__ WuTpT, const float* __restrict__ bu,
    const float* __restrict__ tag_r, const float* __restrict__ tag_z,
    float* __restrict__ out,
    float* __restrict__ zws, float* __restrict__ Sws, ushort* __restrict__ rxws,
    uint* __restrict__ flags, float* __restrict__ finalDup)
{
    __shared__ ushort Abf[16 * 616];
    __shared__ float pbuf[3][64][20];
    const int GBt[8] = {64, 32, 16, 8, 8, 8, 8, 8};
    const int UBt[8] = {32, 16, 8, 4, 4, 4, 4, 4};
    const int offT[8] = {7936, 8064, 8128, 8160, 8176, 8184, 8188, 8190};

    int b = (int)blockIdx.x;
    int li = 0, role = 0, local = 0;
    for (int i = 0; i < 8; ++i) {
        if (b < GBt[i]) { li = i; role = 0; local = b; break; }
        b -= GBt[i];
        if (b < UBt[i]) { li = i; role = 1; local = b; break; }
        b -= UBt[i];
    }
    int m = 128 >> li;
    int off = offT[li], prevOff = off - 2 * m;

    if (!(role == 0 && li == 0)) {
        int wIdx = (role == 0) ? (2 * li - 1) : (2 * li);
        uint wCnt = (role == 0) ? (uint)UBt[li - 1] : (uint)GBt[li];
        if (threadIdx.x == 0) {
            while (__hip_atomic_load(&flags[wIdx * 32], __ATOMIC_RELAXED,
                                     __HIP_MEMORY_SCOPE_AGENT) < wCnt)
                __builtin_amdgcn_s_sleep(8);
        }
        __syncthreads();
        __threadfence();
    }

    if (role == 0)
        gates_body(tag_ids, WArzT, tag_r, tag_z, out, zws, Sws, rxws,
                   off, prevOff, m, local >> 3, local & 7, threadIdx.x, Abf, pbuf);
    else
        u_body(WuTpT, bu, zws, Sws, rxws, out, off, m,
               (li == 7) ? finalDup : nullptr, local >> 2, local & 3,
               threadIdx.x, Abf, pbuf);

    __syncthreads();
    __threadfence();
    if (threadIdx.x == 0)
        atomicAdd(&flags[(2 * li + role) * 32], 1u);
}

extern "C" void kernel_launch(void* const* d_in, const int* in_sizes, int n_in,
                              void* d_out, int out_size, void* d_ws, size_t ws_size,
                              hipStream_t stream)
{
    const int*   word_ids   = (const int*)  d_in[0];
    const int*   tag_ids    = (const int*)  d_in[1];
    const float* word_table = (const float*)d_in[2];
    const float* tag_table  = (const float*)d_in[3];
    const float* Wr         = (const float*)d_in[4];
    const float* br         = (const float*)d_in[5];
    const float* Wz         = (const float*)d_in[6];
    const float* bz         = (const float*)d_in[7];
    const float* Wu         = (const float*)d_in[8];
    const float* bu         = (const float*)d_in[9];
    float* out = (float*)d_out;

    float* tag_r = (float*)d_ws;                  // 18000 f32
    float* tag_z = tag_r + 18000;                 // 18000 f32
    float* zws   = tag_z + 18000;                 // 128*304 f32
    float* Sws   = zws + 128 * 304;               // 128*304 f32
    ushort* rxws = (ushort*)(Sws + 128 * 304);    // 128*608 bf16
    ushort* WArzT = rxws + 128L * 608;            // 40*19*512 bf16
    ushort* WuTpT = WArzT + 40L * 19 * 512;       // 20*19*512
    ushort* WLzuT = WuTpT + 20L * 19 * 512;       // 40*10*512
    uint*  flags  = (uint*)(WLzuT + 40L * 10 * 512);  // 16 phases x 32 uints

    prep_k<<<700, 256, 0, stream>>>(Wr, Wz, Wu, tag_table, br, bz,
                                    WArzT, WuTpT, WLzuT, tag_r, tag_z, flags);

    leaf_mfma_k<<<NLEAF / 16, 512, 0, stream>>>(
        word_ids, tag_ids, word_table, WLzuT, bu, tag_z, out);

    // Big levels m=2048..256: fused single-launch each
    int off = NLEAF, prevOff = 0;
    for (int m = 2048; m >= 256; m >>= 1) {
        level_fused_k<<<m / 16, 512, 0, stream>>>(
            tag_ids, WArzT, WuTpT, bu, tag_r, tag_z, out, off, prevOff, m);
        prevOff = off;
        off += m;
    }

    // Small levels m=128..1: one chained launch (228 blocks, 16 read-poll phases)
    float* finalDup = out + (long)8191 * H;
    chain_k<<<228, 256, 0, stream>>>(
        tag_ids, WArzT, WuTpT, bu, tag_r, tag_z, out, zws, Sws, rxws, flags, finalDup);
}

// Round 24
// 279.167 us; speedup vs baseline: 1.2541x; 1.2541x over previous
//
#include <hip/hip_runtime.h>
#include <math.h>

#define H 300
#define NLEAF 4096

typedef unsigned int  uint;
typedef unsigned short ushort;
typedef __attribute__((ext_vector_type(8))) short  short8;
typedef __attribute__((ext_vector_type(4))) float  f32x4;

__device__ __forceinline__ float sigmoidf_(float x) { return 1.0f / (1.0f + expf(-x)); }

__device__ __forceinline__ ushort f2bf(float f)
{
    uint u = __float_as_uint(f);
    u += 0x7FFF + ((u >> 16) & 1);
    return (ushort)(u >> 16);
}
__device__ __forceinline__ uint2 pack4(float4 v)
{
    uint2 w;
    w.x = (uint)f2bf(v.x) | ((uint)f2bf(v.y) << 16);
    w.y = (uint)f2bf(v.z) | ((uint)f2bf(v.w) << 16);
    return w;
}

// ---- per-wave MFMA GEMM over FRAGMENT-TILED B ----
// B tiled as [colTile][kstep][512 ushorts]: fragment (tile,s) contiguous 1024B;
// lane l reads short8 at frag + l*8 — fully coalesced (16B/lane).
// A in LDS (row stride AS): row=lane%16, k=(s0+s)*32+(lane>>4)*8+i.
// C/D col=lane&15, row=(lane>>4)*4+reg (m89-verified).
template<int NT, int KSTEPS, int KT, int AS>
__device__ __forceinline__ void mfma_gemm(const ushort* A_lds, const ushort* __restrict__ Bt,
                                          int tile0, int s0, int lane, f32x4* acc)
{
    const ushort* Ap = A_lds + (lane & 15) * AS + ((lane >> 4) * 8) + s0 * 32;
    const ushort* Bp[NT];
    #pragma unroll
    for (int t = 0; t < NT; ++t)
        Bp[t] = Bt + ((long)(tile0 + t) * KT + s0) * 512 + lane * 8;

    short8 aA, aB, bA[NT], bB[NT];
    aA = *(const short8*)Ap;
    #pragma unroll
    for (int t = 0; t < NT; ++t) bA[t] = *(const short8*)Bp[t];

    int s = 0;
    #pragma unroll 1
    for (; s + 2 < KSTEPS; s += 2) {
        aB = *(const short8*)(Ap + (s + 1) * 32);
        #pragma unroll
        for (int t = 0; t < NT; ++t) bB[t] = *(const short8*)(Bp[t] + (s + 1) * 512);
        #pragma unroll
        for (int t = 0; t < NT; ++t)
            acc[t] = __builtin_amdgcn_mfma_f32_16x16x32_bf16(aA, bA[t], acc[t], 0, 0, 0);
        aA = *(const short8*)(Ap + (s + 2) * 32);
        #pragma unroll
        for (int t = 0; t < NT; ++t) bA[t] = *(const short8*)(Bp[t] + (s + 2) * 512);
        #pragma unroll
        for (int t = 0; t < NT; ++t)
            acc[t] = __builtin_amdgcn_mfma_f32_16x16x32_bf16(aB, bB[t], acc[t], 0, 0, 0);
    }
    if (KSTEPS - s == 2) {
        aB = *(const short8*)(Ap + (s + 1) * 32);
        #pragma unroll
        for (int t = 0; t < NT; ++t) bB[t] = *(const short8*)(Bp[t] + (s + 1) * 512);
        #pragma unroll
        for (int t = 0; t < NT; ++t)
            acc[t] = __builtin_amdgcn_mfma_f32_16x16x32_bf16(aA, bA[t], acc[t], 0, 0, 0);
        #pragma unroll
        for (int t = 0; t < NT; ++t)
            acc[t] = __builtin_amdgcn_mfma_f32_16x16x32_bf16(aB, bB[t], acc[t], 0, 0, 0);
    } else {
        #pragma unroll
        for (int t = 0; t < NT; ++t)
            acc[t] = __builtin_amdgcn_mfma_f32_16x16x32_bf16(aA, bA[t], acc[t], 0, 0, 0);
    }
}

// ---- merged prep: tiled-bf16 weights (blocks 0-639) + tags (640-699) ----
// WArzT: 40 tiles x 19 ksteps x 512 (cols 0-299 r, 320-619 z)
// WuTpT: 20 tiles x 19 ksteps x 512 (u)
// WLzuT: 40 tiles x 10 ksteps x 512 (cols 0-299 leaf-z, 320-619 leaf-u)
__global__ __launch_bounds__(256) void prep_k(
    const float* __restrict__ Wr, const float* __restrict__ Wz,
    const float* __restrict__ Wu, const float* __restrict__ tag_table,
    const float* __restrict__ br, const float* __restrict__ bz,
    ushort* __restrict__ WArzT, ushort* __restrict__ WuTpT, ushort* __restrict__ WLzuT,
    float* __restrict__ tag_r, float* __restrict__ tag_z)
{
    __shared__ float te[50];
    int b = blockIdx.x;
    int tid = threadIdx.x;
    if (b < 640) {
        int c = b;
        int tile = c >> 4, cl = c & 15;
        int gate = (c >= 320);
        int cc = gate ? c - 320 : c;
        const float* WA = gate ? Wz : Wr;
        for (int o = tid; o < 76; o += 256) {
            int k0 = o * 8;
            ushort tmp[8];
            #pragma unroll
            for (int i = 0; i < 8; ++i) {
                int k = k0 + i;
                float v = 0.f;
                if (cc < 300) {
                    if (k < 300) v = WA[(350 + k) * H + cc];
                    else if (k >= 304 && k < 604) v = WA[(k + 346) * H + cc];
                }
                tmp[i] = f2bf(v);
            }
            int s = k0 >> 5, kk0 = k0 & 31;
            long pos = ((long)(tile * 19 + s)) * 512 + ((kk0 >> 3) * 16 + cl) * 8;
            uint4 w;
            w.x = (uint)tmp[0] | ((uint)tmp[1] << 16);
            w.y = (uint)tmp[2] | ((uint)tmp[3] << 16);
            w.z = (uint)tmp[4] | ((uint)tmp[5] << 16);
            w.w = (uint)tmp[6] | ((uint)tmp[7] << 16);
            *(uint4*)&WArzT[pos] = w;
        }
        const float* WL = gate ? Wu : Wz;
        for (int o = tid; o < 40; o += 256) {
            int k0 = o * 8;
            ushort tmp[8];
            #pragma unroll
            for (int i = 0; i < 8; ++i) {
                int k = k0 + i;
                float v = (cc < 300 && k < 300) ? WL[k * H + cc] : 0.f;
                tmp[i] = f2bf(v);
            }
            int s = k0 >> 5, kk0 = k0 & 31;
            long pos = ((long)(tile * 10 + s)) * 512 + ((kk0 >> 3) * 16 + cl) * 8;
            uint4 w;
            w.x = (uint)tmp[0] | ((uint)tmp[1] << 16);
            w.y = (uint)tmp[2] | ((uint)tmp[3] << 16);
            w.z = (uint)tmp[4] | ((uint)tmp[5] << 16);
            w.w = (uint)tmp[6] | ((uint)tmp[7] << 16);
            *(uint4*)&WLzuT[pos] = w;
        }
        if (c < 320) {
            for (int o = tid; o < 76; o += 256) {
                int k0 = o * 8;
                ushort tmp[8];
                #pragma unroll
                for (int i = 0; i < 8; ++i) {
                    int k = k0 + i;
                    float v = 0.f;
                    if (c < 300) {
                        if (k < 300) v = Wu[(300 + k) * H + c];
                        else if (k >= 304 && k < 604) v = Wu[(k + 296) * H + c];
                    }
                    tmp[i] = f2bf(v);
                }
                int s = k0 >> 5, kk0 = k0 & 31;
                long pos = ((long)(tile * 19 + s)) * 512 + ((kk0 >> 3) * 16 + cl) * 8;
                uint4 w;
                w.x = (uint)tmp[0] | ((uint)tmp[1] << 16);
                w.y = (uint)tmp[2] | ((uint)tmp[3] << 16);
                w.z = (uint)tmp[4] | ((uint)tmp[5] << 16);
                w.w = (uint)tmp[6] | ((uint)tmp[7] << 16);
                *(uint4*)&WuTpT[pos] = w;
            }
        }
    } else {
        int t = b - 640;                 // 0..59
        if (tid < 50) te[tid] = tag_table[t * 50 + tid];
        __syncthreads();
        for (int k = tid; k < H; k += 256) {
            float ar = br[k], az = bz[k];
            #pragma unroll 10
            for (int j = 0; j < 50; ++j) {
                float tv = te[j];
                ar = fmaf(tv, Wr[(H + j) * H + k], ar);
                az = fmaf(tv, Wz[(H + j) * H + k], az);
            }
            tag_r[t * H + k] = ar;
            tag_z[t * H + k] = az;
        }
    }
}

// ---- Leaf (MFMA, 512 thr / 8 waves): waves 0-3 z-cols, waves 4-7 u-cols.
__global__ __launch_bounds__(512, 1) void leaf_mfma_k(
    const int* __restrict__ word_ids, const int* __restrict__ tag_ids,
    const float* __restrict__ word_table, const ushort* __restrict__ WLzuT,
    const float* __restrict__ bu, const float* __restrict__ tag_z,
    float* __restrict__ out)
{
    __shared__ ushort Abf[16 * 328];
    __shared__ float zbuf[16][304];
    int tid = threadIdx.x;
    int node0 = blockIdx.x * 16;

    for (int idx = tid; idx < 16 * 82; idx += 512) {
        int j = idx / 82, q = idx - j * 82;
        char* rowb = (char*)(Abf + j * 328);
        if (q < 75) {
            float4 v = ((const float4*)(word_table + (long)word_ids[node0 + j] * H))[q];
            *(uint2*)(rowb + q * 8) = pack4(v);
        } else {
            *(uint2*)(rowb + q * 8) = make_uint2(0u, 0u);
        }
    }
    __syncthreads();

    int wv = tid >> 6, lane = tid & 63;
    int jrow = (lane >> 4) * 4;

    f32x4 acc[5];
    #pragma unroll
    for (int t = 0; t < 5; ++t) acc[t] = (f32x4)(0.f);

    if (wv < 4) {
        mfma_gemm<5, 10, 10, 328>(Abf, WLzuT, wv * 5, 0, lane, acc);
        int tg[4];
        #pragma unroll
        for (int q = 0; q < 4; ++q) tg[q] = tag_ids[node0 + jrow + q];
        #pragma unroll
        for (int t = 0; t < 5; ++t) {
            int c = wv * 80 + t * 16 + (lane & 15);
            #pragma unroll
            for (int q = 0; q < 4; ++q)
                if (c < 300) zbuf[jrow + q][c] = sigmoidf_(acc[t][q] + tag_z[tg[q] * H + c]);
        }
    } else {
        mfma_gemm<5, 10, 10, 328>(Abf, WLzuT, 20 + (wv - 4) * 5, 0, lane, acc);
    }
    __syncthreads();
    if (wv >= 4) {
        #pragma unroll
        for (int t = 0; t < 5; ++t) {
            int c = (wv - 4) * 80 + t * 16 + (lane & 15);
            #pragma unroll
            for (int q = 0; q < 4; ++q) {
                if (c < 300) {
                    int jn = jrow + q;
                    float u = tanhf(acc[t][q] + bu[c]);
                    out[(long)(node0 + jn) * H + c] = (1.f - zbuf[jn][c]) * u;
                }
            }
        }
    }
}

// ---- Fused internal level (512 thr / 8 waves, 16 nodes), any m ----
__device__ __forceinline__ void fused_body(
    const int* __restrict__ tag_ids, const ushort* __restrict__ WArzT,
    const ushort* __restrict__ WuTpT, const float* __restrict__ bu,
    const float* __restrict__ tag_r, const float* __restrict__ tag_z,
    float* __restrict__ out, int off, int prevOff, int m, float* __restrict__ dup,
    int node0, int tid, ushort* Abf, float (*zbuf)[304], float (*pbuf)[64][21])
{
    for (int idx = tid; idx < 16 * 154; idx += 512) {
        int j = idx / 154, q = idx - j * 154;
        char* rowb = (char*)(Abf + j * 616);
        bool valid = (node0 + j) < m;
        if (q < 75) {
            uint2 w = make_uint2(0u, 0u);
            if (valid) {
                float4 v = ((const float4*)(out + (long)(prevOff + 2 * (node0 + j)) * H))[q];
                w = pack4(v);
            }
            *(uint2*)(rowb + q * 8) = w;
        } else if (q < 150) {
            int qq = q - 75;
            uint2 w = make_uint2(0u, 0u);
            if (valid) {
                float4 v = ((const float4*)(out + (long)(prevOff + 2 * (node0 + j) + 1) * H))[qq];
                w = pack4(v);
            }
            *(uint2*)(rowb + 608 + qq * 8) = w;
        } else {
            int pb = (q == 150) ? 600 : (1208 + (q - 151) * 8);
            *(uint2*)(rowb + pb) = make_uint2(0u, 0u);
        }
    }
    __syncthreads();

    int wv = tid >> 6, lane = tid & 63;
    int jrow = (lane >> 4) * 4;
    int tg[4];
    #pragma unroll
    for (int q = 0; q < 4; ++q) {
        int gn = node0 + jrow + q;
        tg[q] = tag_ids[off + (gn < m ? gn : 0)];
    }

    f32x4 accG[5];
    #pragma unroll
    for (int t = 0; t < 5; ++t) accG[t] = (f32x4)(0.f);
    mfma_gemm<5, 19, 19, 616>(Abf, WArzT, wv * 5, 0, lane, accG);
    __syncthreads();

    float Sr[5][4];
    if (wv < 4) {
        #pragma unroll
        for (int t = 0; t < 5; ++t) {
            int c = wv * 80 + t * 16 + (lane & 15);
            #pragma unroll
            for (int q = 0; q < 4; ++q) {
                int jn = jrow + q, gn = node0 + jn;
                if (c < 300 && gn < m) {
                    float lh = out[(long)(prevOff + 2 * gn) * H + c];
                    float rh = out[(long)(prevOff + 2 * gn + 1) * H + c];
                    float r  = sigmoidf_(accG[t][q] + tag_r[tg[q] * H + c]);
                    Sr[t][q] = lh + rh;
                    Abf[jn * 616 + c]       = f2bf(r * lh);
                    Abf[jn * 616 + 304 + c] = f2bf(r * rh);
                }
            }
        }
    } else {
        #pragma unroll
        for (int t = 0; t < 5; ++t) {
            int cz = (wv - 4) * 80 + t * 16 + (lane & 15);
            #pragma unroll
            for (int q = 0; q < 4; ++q) {
                int jn = jrow + q, gn = node0 + jn;
                if (cz < 300 && gn < m)
                    zbuf[jn][cz] = sigmoidf_(accG[t][q] + tag_z[tg[q] * H + cz]);
            }
        }
    }
    __syncthreads();

    f32x4 accU[5];
    #pragma unroll
    for (int t = 0; t < 5; ++t) accU[t] = (f32x4)(0.f);
    if (wv < 4) {
        mfma_gemm<5, 10, 19, 616>(Abf, WuTpT, wv * 5, 0, lane, accU);
    } else {
        mfma_gemm<5, 9, 19, 616>(Abf, WuTpT, (wv - 4) * 5, 10, lane, accU);
        #pragma unroll
        for (int t = 0; t < 5; ++t)
            #pragma unroll
            for (int q = 0; q < 4; ++q)
                pbuf[wv - 4][lane][t * 4 + q] = accU[t][q];
    }
    __syncthreads();
    if (wv < 4) {
        #pragma unroll
        for (int t = 0; t < 5; ++t) {
            int c = wv * 80 + t * 16 + (lane & 15);
            #pragma unroll
            for (int q = 0; q < 4; ++q) {
                int jn = jrow + q, gn = node0 + jn;
                if (c < 300 && gn < m) {
                    float a = accU[t][q] + pbuf[wv][lane][t * 4 + q];
                    float u = tanhf(a + bu[c]);
                    float z = zbuf[jn][c];
                    float h = z * Sr[t][q] + (1.f - z) * u;
                    out[(long)(off + gn) * H + c] = h;
                    if (dup && gn == 0) dup[c] = h;
                }
            }
        }
    }
}

__global__ __launch_bounds__(512, 1) void level_fused_k(
    const int* __restrict__ tag_ids, const ushort* __restrict__ WArzT,
    const ushort* __restrict__ WuTpT, const float* __restrict__ bu,
    const float* __restrict__ tag_r, const float* __restrict__ tag_z,
    float* __restrict__ out, int off, int prevOff, int m)
{
    __shared__ ushort Abf[16 * 616];
    __shared__ float zbuf[16][304];
    __shared__ float pbuf[4][64][21];
    fused_body(tag_ids, WArzT, WuTpT, bu, tag_r, tag_z, out, off, prevOff, m,
               nullptr, blockIdx.x * 16, threadIdx.x, Abf, zbuf, pbuf);
}

// ---- Tail: levels m=8,4,2,1 in ONE block (intra-block global-write
// visibility across __syncthreads — R8/R15-validated).
__global__ __launch_bounds__(512, 1) void tail4_k(
    const int* __restrict__ tag_ids, const ushort* __restrict__ WArzT,
    const ushort* __restrict__ WuTpT, const float* __restrict__ bu,
    const float* __restrict__ tag_r, const float* __restrict__ tag_z,
    float* __restrict__ out, float* __restrict__ finalDup)
{
    __shared__ ushort Abf[16 * 616];
    __shared__ float zbuf[16][304];
    __shared__ float pbuf[4][64][21];
    int off = 8176, prevOff = 8160;
    for (int m = 8; m >= 1; m >>= 1) {
        fused_body(tag_ids, WArzT, WuTpT, bu, tag_r, tag_z, out, off, prevOff, m,
                   (m == 1) ? finalDup : nullptr, 0, threadIdx.x, Abf, zbuf, pbuf);
        __syncthreads();
        prevOff = off;
        off += m;
    }
}

extern "C" void kernel_launch(void* const* d_in, const int* in_sizes, int n_in,
                              void* d_out, int out_size, void* d_ws, size_t ws_size,
                              hipStream_t stream)
{
    const int*   word_ids   = (const int*)  d_in[0];
    const int*   tag_ids    = (const int*)  d_in[1];
    const float* word_table = (const float*)d_in[2];
    const float* tag_table  = (const float*)d_in[3];
    const float* Wr         = (const float*)d_in[4];
    const float* br         = (const float*)d_in[5];
    const float* Wz         = (const float*)d_in[6];
    const float* bz         = (const float*)d_in[7];
    const float* Wu         = (const float*)d_in[8];
    const float* bu         = (const float*)d_in[9];
    float* out = (float*)d_out;

    float* tag_r = (float*)d_ws;                  // 18000 f32
    float* tag_z = tag_r + 18000;                 // 18000 f32
    ushort* WArzT = (ushort*)(tag_z + 18000);     // 40*19*512 bf16
    ushort* WuTpT = WArzT + 40L * 19 * 512;       // 20*19*512
    ushort* WLzuT = WuTpT + 20L * 19 * 512;       // 40*10*512

    prep_k<<<700, 256, 0, stream>>>(Wr, Wz, Wu, tag_table, br, bz,
                                    WArzT, WuTpT, WLzuT, tag_r, tag_z);

    leaf_mfma_k<<<NLEAF / 16, 512, 0, stream>>>(
        word_ids, tag_ids, word_table, WLzuT, bu, tag_z, out);

    // Levels m=2048..16: one fused launch each
    int off = NLEAF, prevOff = 0;
    for (int m = 2048; m >= 16; m >>= 1) {
        level_fused_k<<<m / 16, 512, 0, stream>>>(
            tag_ids, WArzT, WuTpT, bu, tag_r, tag_z, out, off, prevOff, m);
        prevOff = off;
        off += m;
    }

    // Levels m=8..1: one single-block launch
    float* finalDup = out + (long)8191 * H;
    tail4_k<<<1, 512, 0, stream>>>(
        tag_ids, WArzT, WuTpT, bu, tag_r, tag_z, out, finalDup);
}